// Round 10
// baseline (123.326 us; speedup 1.0000x reference)
//
#include <hip/hip_runtime.h>

#define N_NODES 100000
#define N_EDGES 1600000
#define D_FEAT  64
#define NFEAT_ELEM (N_NODES * D_FEAT)                    // 6,400,000

#define BUCK_SHIFT 6
#define BUCK_NODES 64                                    // nodes per bucket
#define NBUCK ((N_NODES + BUCK_NODES - 1) / BUCK_NODES)  // 1563
#define CUR_PAD 16

#define BIN_BLK 256
#define BIN_EPT 16
#define BIN_CHUNK (BIN_BLK * BIN_EPT)                    // 4096 edges/block
#define NCHUNK ((N_EDGES + BIN_CHUNK - 1) / BIN_CHUNK)   // 391

#define HIST_BLOCKS 256

// gather: one block per 64-node bucket, no discard
#define GB_BLK   256                                     // 4 waves
#define GB_EPT   6                                       // 6*256=1536 >= max bucket (~1200)
#define GB_CAP   (GB_BLK * GB_EPT)                       // 1536

typedef float          vf4 __attribute__((ext_vector_type(4)));
typedef float          vf2 __attribute__((ext_vector_type(2)));
typedef int            vi4 __attribute__((ext_vector_type(4)));
typedef unsigned short vu4 __attribute__((ext_vector_type(4)));
typedef unsigned short ushort_t;

// ---------------------------------------------------------------------------
// Workspace layout:
//   bcnt  : int[NBUCK]
//   done  : int                  (last-block flag, zeroed each call)
//   bbase : int[NBUCK+1]
//   bcur  : int[NBUCK*CUR_PAD]
//   ep    : int2[N_EDGES]        (.x = local_dst<<24 | src, .y = w bits)
//   featb : ushort[NFEAT_ELEM]   bf16 feature copy (12.8 MB)
// ---------------------------------------------------------------------------
#define OFF_BCNT  0
#define OFF_DONE  (OFF_BCNT + NBUCK * 4)
#define OFF_BBASE (OFF_DONE + 4)
#define OFF_BCUR  (OFF_BBASE + (NBUCK + 1) * 4)
#define OFF_EP    (((OFF_BCUR + NBUCK * CUR_PAD * 4) + 255) & ~255)
#define OFF_FEATB (OFF_EP + N_EDGES * 8)
#define WS_MED    (size_t)OFF_FEATB
#define WS_FULL   (size_t)(OFF_FEATB + (size_t)NFEAT_ELEM * 2)

// fp32 -> bf16 (RNE) conversion of feat; also zeroes bcnt + done flag.
__global__ void k_prep(const float* __restrict__ feat, ushort_t* __restrict__ featb,
                       int* __restrict__ bcnt, int* __restrict__ done) {
    int i = blockIdx.x * blockDim.x + threadIdx.x;       // float4 index
    if (i < NBUCK) bcnt[i] = 0;
    if (i == NBUCK) *done = 0;
    if (i < NFEAT_ELEM / 4) {
        vf4 x = ((const vf4*)feat)[i];
        vu4 r;
#pragma unroll
        for (int k = 0; k < 4; ++k) {
            unsigned b = __float_as_uint(x[k]);
            r[k] = (ushort_t)((b + 0x7fffu + ((b >> 16) & 1u)) >> 16);
        }
        __builtin_nontemporal_store(r, (vu4*)featb + i);
    }
}

// Histogram + fused exclusive scan (last-block-done pattern).
__global__ __launch_bounds__(256) void k_bhist(const int* __restrict__ dst,
                                               int* __restrict__ bcnt,
                                               int* __restrict__ done,
                                               int* __restrict__ bbase,
                                               int* __restrict__ bcur) {
    __shared__ int h[NBUCK];
    const int t = threadIdx.x;
    for (int i = t; i < NBUCK; i += 256) h[i] = 0;
    __syncthreads();
    const int n4 = N_EDGES / 4;                          // 400,000 exact
    const int stride = gridDim.x * 256;
    const vi4* d4 = (const vi4*)dst;
    for (int i = blockIdx.x * 256 + t; i < n4; i += stride) {
        vi4 v = __builtin_nontemporal_load(d4 + i);
        atomicAdd(&h[v.x >> BUCK_SHIFT], 1);
        atomicAdd(&h[v.y >> BUCK_SHIFT], 1);
        atomicAdd(&h[v.z >> BUCK_SHIFT], 1);
        atomicAdd(&h[v.w >> BUCK_SHIFT], 1);
    }
    __syncthreads();
    for (int i = t; i < NBUCK; i += 256)
        if (h[i]) atomicAdd(&bcnt[i], h[i]);

    // last block performs the scan (device-scope atomics; fence for ordering)
    __threadfence();
    __shared__ int last;
    if (t == 0) last = (atomicAdd(done, 1) == (int)gridDim.x - 1) ? 1 : 0;
    __syncthreads();
    if (!last) return;

    const int per = (NBUCK + 255) / 256;                 // 7
    const int lo = t * per;
    const int hi = (lo + per < NBUCK) ? lo + per : NBUCK;
    int s = 0;
    for (int i = lo; i < hi; ++i)
        s += __hip_atomic_load(&bcnt[i], __ATOMIC_RELAXED, __HIP_MEMORY_SCOPE_AGENT);
    __shared__ int ss[256];
    ss[t] = s;
    __syncthreads();
    for (int off = 1; off < 256; off <<= 1) {
        int x = (t >= off) ? ss[t - off] : 0;
        __syncthreads();
        ss[t] += x;
        __syncthreads();
    }
    int run = ss[t] - s;                                 // exclusive
    for (int i = lo; i < hi; ++i) {
        int c = __hip_atomic_load(&bcnt[i], __ATOMIC_RELAXED, __HIP_MEMORY_SCOPE_AGENT);
        bbase[i] = run;
        bcur[i * CUR_PAD] = run;
        run += c;
    }
    if (t == 255) bbase[NBUCK] = N_EDGES;
}

// Chunked write-combining binning pass (now 1563 fine buckets).
__global__ __launch_bounds__(BIN_BLK) void k_bin(const int* __restrict__ src,
                                                 const int* __restrict__ dst,
                                                 const float* __restrict__ weight,
                                                 int* __restrict__ bcur,
                                                 int2* __restrict__ ep) {
    __shared__ int lcnt[NBUCK];
    __shared__ int lbase[NBUCK];
    const int t = threadIdx.x;
    const int e0 = blockIdx.x * BIN_CHUNK;
    for (int i = t; i < NBUCK; i += BIN_BLK) lcnt[i] = 0;
    __syncthreads();
    int bk[BIN_EPT], rk[BIN_EPT], xk[BIN_EPT], wk[BIN_EPT];
#pragma unroll
    for (int k = 0; k < BIN_EPT; ++k) {
        const int e = e0 + t + k * BIN_BLK;              // coalesced
        bk[k] = -1;
        if (e < N_EDGES) {
            int v = __builtin_nontemporal_load(dst + e);
            int s = __builtin_nontemporal_load(src + e);
            wk[k] = __builtin_nontemporal_load((const int*)weight + e);
            int b = v >> BUCK_SHIFT;
            bk[k] = b;
            xk[k] = ((v & (BUCK_NODES - 1)) << 24) | s;  // src < 2^17
            rk[k] = atomicAdd(&lcnt[b], 1);
        }
    }
    __syncthreads();
    for (int i = t; i < NBUCK; i += BIN_BLK) {
        int c = lcnt[i];
        if (c) lbase[i] = atomicAdd(&bcur[i * CUR_PAD], c);
    }
    __syncthreads();
#pragma unroll
    for (int k = 0; k < BIN_EPT; ++k)
        if (bk[k] >= 0) ep[lbase[bk[k]] + rk[k]] = make_int2(xk[k], wk[k]);
}

// Sort-in-LDS + register-accumulator gather; 1 block per 64-node bucket.
// Phase 2: read own bucket's edges (ALL kept), LDS rank. Phase 3: 64-entry
// scan. Phase 4: scatter (s,w) pairs into sorted int2 list. Phase 5: per-node
// register accumulation; half-wave pair trick (lane<32 even edges, lane>=32
// odd; each lane loads a packed pair of dims) -> one instr covers 2 rows;
// shfl_xor(32) merges. One NT float2 store per node, bias fused. No atomics.
template <int BF16>
__global__ __launch_bounds__(GB_BLK, 6) void k_sgather(const float* __restrict__ feat,
                                                       const ushort_t* __restrict__ featb,
                                                       const float* __restrict__ bias,
                                                       const int* __restrict__ bbase,
                                                       const int2* __restrict__ ep,
                                                       float* __restrict__ out) {
    __shared__ int2 sxw[GB_CAP];                         // 12 KB
    __shared__ int  cnt[BUCK_NODES];
    __shared__ int  off[BUCK_NODES];

    const int t = threadIdx.x;
    const int lane = t & 63;
    const int wid = t >> 6;                              // 0..3
    const int bk = blockIdx.x;
    const int g0 = bbase[bk];
    const int g1 = bbase[bk + 1];
    const int nE = g1 - g0;
    const int nEc = nE > GB_CAP ? GB_CAP : nE;

    if (t < BUCK_NODES) cnt[t] = 0;
    __syncthreads();

    // Phase 2: load + rank (every edge belongs to this block)
    int   xk[GB_EPT];
    float wk[GB_EPT];
    int   rk[GB_EPT];
#pragma unroll
    for (int k = 0; k < GB_EPT; ++k) {
        const int idx = t + k * GB_BLK;
        xk[k] = -1;
        if (idx < nEc) {
            int2 e = ep[g0 + idx];
            xk[k] = e.x;
            wk[k] = __int_as_float(e.y);
            rk[k] = atomicAdd(&cnt[(unsigned)e.x >> 24], 1);
        }
    }
    __syncthreads();

    // Phase 3: inclusive scan cnt -> off (64 entries)
    if (t < BUCK_NODES) off[t] = cnt[t];
    __syncthreads();
    for (int d = 1; d < BUCK_NODES; d <<= 1) {
        int v = 0;
        if (t < BUCK_NODES && t >= d) v = off[t - d];
        __syncthreads();
        if (t < BUCK_NODES) off[t] += v;
        __syncthreads();
    }

    // Phase 4: scatter into sorted list (pos < nEc <= GB_CAP always)
#pragma unroll
    for (int k = 0; k < GB_EPT; ++k) {
        if (xk[k] != -1) {
            int r = (unsigned)xk[k] >> 24;
            int pos = off[r] - cnt[r] + rk[k];
            sxw[pos] = make_int2(xk[k] & 0xFFFFFF, __float_as_int(wk[k]));
        }
    }
    __syncthreads();

    // Phase 5: per-node register accumulation
    const int col = lane & 31;
    const int half = lane >> 5;
    const vf2 b2 = ((const vf2*)bias)[col];
    for (int rr = 0; rr < 16; ++rr) {
        const int r = wid * 16 + rr;
        const int c = cnt[r];
        const int e0 = off[r] - c;
        float a0 = 0.f, a1 = 0.f;
        for (int i = 0; i < c; i += 8) {
#pragma unroll
            for (int k = 0; k < 4; ++k) {
                const int ei = i + 2 * k + half;
                int2 e = (ei < c) ? sxw[e0 + ei] : make_int2(0, 0);
                const float w = __int_as_float(e.y);
                if (BF16) {
                    unsigned d = *((const unsigned*)(featb + e.x * D_FEAT) + col);
                    a0 = fmaf(w, __uint_as_float(d << 16), a0);
                    a1 = fmaf(w, __uint_as_float(d & 0xFFFF0000u), a1);
                } else {
                    vf2 fv = *((const vf2*)(feat + e.x * D_FEAT) + col);
                    a0 = fmaf(w, fv.x, a0);
                    a1 = fmaf(w, fv.y, a1);
                }
            }
        }
        a0 += __shfl_xor(a0, 32);
        a1 += __shfl_xor(a1, 32);
        const int node = bk * BUCK_NODES + r;
        if (half == 0 && node < N_NODES) {
            vf2 o = {a0 + b2.x, a1 + b2.y};
            __builtin_nontemporal_store(o, (vf2*)(out + (size_t)node * D_FEAT) + col);
        }
    }
    __syncthreads();

    // Safety tail (nE > GB_CAP; statistically never). Same-block rows only;
    // the barrier orders it after the epilogue stores.
    for (int idx = nEc + t; idx < nE; idx += GB_BLK) {
        int2 e = ep[g0 + idx];
        int node = bk * BUCK_NODES + ((unsigned)e.x >> 24);
        int s = e.x & 0xFFFFFF;
        float w = __int_as_float(e.y);
        for (int d2 = 0; d2 < D_FEAT; ++d2)
            atomicAdd(&out[(size_t)node * D_FEAT + d2], w * feat[s * D_FEAT + d2]);
    }
}

// ---------------- fallback (ws too small): direct atomic path ---------------
__global__ void init_out_kernel(const float* __restrict__ bias,
                                float* __restrict__ out) {
    int i = blockIdx.x * blockDim.x + threadIdx.x;
    if (i < N_NODES * D_FEAT) out[i] = bias[i & (D_FEAT - 1)];
}

__global__ void edge_scatter_kernel(const float* __restrict__ feat,
                                    const float* __restrict__ weight,
                                    const int* __restrict__ src,
                                    const int* __restrict__ dst,
                                    float* __restrict__ out) {
    int e = blockIdx.x * 4 + (threadIdx.x >> 6);
    int lane = threadIdx.x & 63;
    if (e < N_EDGES) {
        atomicAdd(&out[dst[e] * D_FEAT + lane], weight[e] * feat[src[e] * D_FEAT + lane]);
    }
}

extern "C" void kernel_launch(void* const* d_in, const int* in_sizes, int n_in,
                              void* d_out, int out_size, void* d_ws, size_t ws_size,
                              hipStream_t stream) {
    const float* feat   = (const float*)d_in[0];
    const float* weight = (const float*)d_in[1];
    const float* bias   = (const float*)d_in[2];
    const int*   src    = (const int*)d_in[3];
    const int*   dst    = (const int*)d_in[4];
    float* out = (float*)d_out;

    if (ws_size < WS_MED) {
        int total = N_NODES * D_FEAT;
        init_out_kernel<<<(total + 255) / 256, 256, 0, stream>>>(bias, out);
        edge_scatter_kernel<<<(N_EDGES + 3) / 4, 256, 0, stream>>>(feat, weight, src, dst, out);
        return;
    }

    char* ws = (char*)d_ws;
    int*      bcnt  = (int*)(ws + OFF_BCNT);
    int*      done  = (int*)(ws + OFF_DONE);
    int*      bbase = (int*)(ws + OFF_BBASE);
    int*      bcur  = (int*)(ws + OFF_BCUR);
    int2*     ep    = (int2*)(ws + OFF_EP);
    ushort_t* featb = (ushort_t*)(ws + OFF_FEATB);
    const bool use_bf16 = (ws_size >= WS_FULL);

    if (use_bf16) {
        k_prep<<<(NFEAT_ELEM / 4 + 255) / 256, 256, 0, stream>>>(feat, featb, bcnt, done);
    } else {
        (void)hipMemsetAsync(bcnt, 0, NBUCK * 4 + 4, stream);   // bcnt + done
    }
    k_bhist<<<HIST_BLOCKS, 256, 0, stream>>>(dst, bcnt, done, bbase, bcur);
    k_bin<<<NCHUNK, BIN_BLK, 0, stream>>>(src, dst, weight, bcur, ep);
    if (use_bf16)
        k_sgather<1><<<NBUCK, GB_BLK, 0, stream>>>(feat, featb, bias, bbase, ep, out);
    else
        k_sgather<0><<<NBUCK, GB_BLK, 0, stream>>>(feat, featb, bias, bbase, ep, out);
}

// Round 11
// 96.916 us; speedup vs baseline: 1.2725x; 1.2725x over previous
//
#include <hip/hip_runtime.h>

#define N_NODES 100000
#define N_EDGES 1600000
#define D_FEAT  64
#define NFEAT_ELEM (N_NODES * D_FEAT)                    // 6,400,000

#define BUCK_SHIFT 6
#define BUCK_NODES 64
#define NBUCK ((N_NODES + BUCK_NODES - 1) / BUCK_NODES)  // 1563
#define NB1 (NBUCK + 1)

#define CHUNK   4096
#define NCHUNK  ((N_EDGES + CHUNK - 1) / CHUNK)          // 391
#define BIN_BLK 256
#define BIN_EPT (CHUNK / BIN_BLK)                        // 16
#define SCAN_PER ((NBUCK + BIN_BLK - 1) / BIN_BLK)       // 7
#define PREP_BLOCKS 128

#define GB_BLK  256
#define GB_CAP  1536                                     // mean bucket 1024, +16 sigma

typedef float          vf4 __attribute__((ext_vector_type(4)));
typedef float          vf2 __attribute__((ext_vector_type(2)));
typedef int            vi2 __attribute__((ext_vector_type(2)));
typedef unsigned short vu4 __attribute__((ext_vector_type(4)));
typedef unsigned short ushort_t;

// ---------------------------------------------------------------------------
// Workspace: tbl (chunk-major run offsets) | ep (chunk-major sorted payload) |
//            featb (bf16 feat). No histogram/scan/cursor state at all.
// ---------------------------------------------------------------------------
#define TBL_BYTES (NCHUNK * NB1 * 2)
#define OFF_TBL   0
#define OFF_EP    ((TBL_BYTES + 255) & ~255)
#define OFF_FEATB (OFF_EP + N_EDGES * 8)
#define WS_MED    (size_t)OFF_FEATB
#define WS_FULL   (size_t)(OFF_FEATB + (size_t)NFEAT_ELEM * 2)

// Chunk-major binning + fused bf16 prep (role-split grid).
// Bin block: LDS count -> blocked scan -> LDS scatter -> ONE contiguous NT
// stream write of the sorted 32KB chunk + its ushort offset row. No global
// atomics, no write amplification.
template <int BF16>
__global__ __launch_bounds__(BIN_BLK) void k_bin(const int* __restrict__ src,
                                                 const int* __restrict__ dst,
                                                 const float* __restrict__ weight,
                                                 const float* __restrict__ feat,
                                                 ushort_t* __restrict__ featb,
                                                 ushort_t* __restrict__ tbl,
                                                 vi2* __restrict__ ep) {
    if (blockIdx.x >= NCHUNK) {                          // prep role
        if (!BF16) return;
        const int stride = PREP_BLOCKS * BIN_BLK;
        for (int i = (blockIdx.x - NCHUNK) * BIN_BLK + threadIdx.x;
             i < NFEAT_ELEM / 4; i += stride) {
            vf4 x = ((const vf4*)feat)[i];
            vu4 r;
#pragma unroll
            for (int k = 0; k < 4; ++k) {
                unsigned bb = __float_as_uint(x[k]);
                r[k] = (ushort_t)((bb + 0x7fffu + ((bb >> 16) & 1u)) >> 16);
            }
            __builtin_nontemporal_store(r, (vu4*)featb + i);
        }
        return;
    }

    __shared__ vi2 schunk[CHUNK];                        // 32 KB
    __shared__ int lcnt[NBUCK];                          // 6.25 KB
    __shared__ int ss[BIN_BLK];
    const int t = threadIdx.x;
    const int c = blockIdx.x;
    const int e0 = c * CHUNK;
    const int chunkN = (N_EDGES - e0 < CHUNK) ? (N_EDGES - e0) : CHUNK;

    for (int i = t; i < NBUCK; i += BIN_BLK) lcnt[i] = 0;
    __syncthreads();

    int bk[BIN_EPT], rk[BIN_EPT], xk[BIN_EPT], wk[BIN_EPT];
#pragma unroll
    for (int k = 0; k < BIN_EPT; ++k) {
        const int e = e0 + t + k * BIN_BLK;              // coalesced
        bk[k] = -1;
        if (e < N_EDGES) {
            int v = __builtin_nontemporal_load(dst + e);
            int s = __builtin_nontemporal_load(src + e);
            wk[k] = __builtin_nontemporal_load((const int*)weight + e);
            bk[k] = v >> BUCK_SHIFT;
            xk[k] = ((v & (BUCK_NODES - 1)) << 24) | s;  // src < 2^17
            rk[k] = atomicAdd(&lcnt[bk[k]], 1);
        }
    }
    __syncthreads();

    // blocked exclusive scan of lcnt (1563) -> in-place starts + table row
    int v7[SCAN_PER];
    const int lo = t * SCAN_PER;
    int s = 0;
#pragma unroll
    for (int k = 0; k < SCAN_PER; ++k) {
        const int i = lo + k;
        v7[k] = (i < NBUCK) ? lcnt[i] : 0;
        s += v7[k];
    }
    ss[t] = s;
    __syncthreads();
    for (int off = 1; off < BIN_BLK; off <<= 1) {
        int x = (t >= off) ? ss[t - off] : 0;
        __syncthreads();
        ss[t] += x;
        __syncthreads();
    }
    int run = ss[t] - s;
    ushort_t* row = tbl + (size_t)c * NB1;
#pragma unroll
    for (int k = 0; k < SCAN_PER; ++k) {
        const int i = lo + k;
        if (i < NBUCK) {
            row[i] = (ushort_t)run;
            lcnt[i] = run;
            run += v7[k];
        }
    }
    if (t == BIN_BLK - 1) row[NBUCK] = (ushort_t)chunkN;
    __syncthreads();

#pragma unroll
    for (int k = 0; k < BIN_EPT; ++k)
        if (bk[k] >= 0) schunk[lcnt[bk[k]] + rk[k]] = (vi2){xk[k], wk[k]};
    __syncthreads();

    for (int i = t; i < chunkN; i += BIN_BLK)            // contiguous stream
        __builtin_nontemporal_store(schunk[i], ep + e0 + i);
}

// One block per 64-node bucket. Phase 1: walk 391 table runs (2 chunks per
// thread), deterministic staging via run-length scan (no global state).
// Phase 2-4: LDS count/scan/scatter into node-sorted list. Phase 5: register
// accumulation with half-wave pair trick; one NT float2 store/node, bias
// fused. No global atomics on the hot path.
template <int BF16>
__global__ __launch_bounds__(GB_BLK) void k_sgather(const float* __restrict__ feat,
                                                    const ushort_t* __restrict__ featb,
                                                    const float* __restrict__ bias,
                                                    const ushort_t* __restrict__ tbl,
                                                    const vi2* __restrict__ ep,
                                                    float* __restrict__ out) {
    __shared__ vi2 stg[GB_CAP];                          // 12 KB
    __shared__ vi2 srt[GB_CAP];                          // 12 KB
    __shared__ int cnt[BUCK_NODES], cnt2[BUCK_NODES], off[BUCK_NODES];
    __shared__ int ss[GB_BLK];

    const int t = threadIdx.x;
    const int lane = t & 63;
    const int wid = t >> 6;
    const int b = blockIdx.x;
    if (t < BUCK_NODES) { cnt[t] = 0; cnt2[t] = 0; }

    // run descriptors: chunks c0 = t, c1 = t + 256
    const int c0 = t, c1 = t + GB_BLK;
    int o00 = 0, o01 = 0, o10 = 0, o11 = 0;
    if (c0 < NCHUNK) {
        o00 = tbl[(size_t)c0 * NB1 + b];
        o01 = tbl[(size_t)c0 * NB1 + b + 1];
    }
    if (c1 < NCHUNK) {
        o10 = tbl[(size_t)c1 * NB1 + b];
        o11 = tbl[(size_t)c1 * NB1 + b + 1];
    }
    const int len = (o01 - o00) + (o11 - o10);
    ss[t] = len;
    __syncthreads();
    for (int o = 1; o < GB_BLK; o <<= 1) {
        int x = (t >= o) ? ss[t - o] : 0;
        __syncthreads();
        ss[t] += x;
        __syncthreads();
    }
    const int base = ss[t] - len;
    const int nTot = ss[GB_BLK - 1];

    // pass 1: deterministic staging + count
    int g = base;
    for (int e = o00; e < o01; ++e, ++g)
        if (g < GB_CAP) {
            vi2 v = ep[c0 * CHUNK + e];
            stg[g] = v;
            atomicAdd(&cnt[(unsigned)v.x >> 24], 1);
        }
    for (int e = o10; e < o11; ++e, ++g)
        if (g < GB_CAP) {
            vi2 v = ep[c1 * CHUNK + e];
            stg[g] = v;
            atomicAdd(&cnt[(unsigned)v.x >> 24], 1);
        }
    __syncthreads();

    // inclusive scan cnt -> off (64 entries)
    if (t < BUCK_NODES) off[t] = cnt[t];
    __syncthreads();
    for (int d = 1; d < BUCK_NODES; d <<= 1) {
        int x = 0;
        if (t < BUCK_NODES && t >= d) x = off[t - d];
        __syncthreads();
        if (t < BUCK_NODES) off[t] += x;
        __syncthreads();
    }

    // pass 2: scatter into node-sorted list
    const int nStg = nTot < GB_CAP ? nTot : GB_CAP;
    for (int i = t; i < nStg; i += GB_BLK) {
        vi2 v = stg[i];
        int r = (unsigned)v.x >> 24;
        int pos = off[r] - cnt[r] + atomicAdd(&cnt2[r], 1);
        srt[pos] = v;
    }
    __syncthreads();

    // phase 5: per-node register accumulation
    const int col = lane & 31;
    const int half = lane >> 5;
    const vf2 b2 = ((const vf2*)bias)[col];
    for (int rr = 0; rr < 16; ++rr) {
        const int r = wid * 16 + rr;
        const int cc = cnt[r];
        const int s0 = off[r] - cc;
        float a0 = 0.f, a1 = 0.f;
        for (int i = 0; i < cc; i += 8) {
#pragma unroll
            for (int k = 0; k < 4; ++k) {
                const int ei = i + 2 * k + half;
                vi2 e = (ei < cc) ? srt[s0 + ei] : (vi2){0, 0};
                const float w = __int_as_float(e.y);
                const int sidx = e.x & 0xFFFFFF;
                if (BF16) {
                    unsigned d = *((const unsigned*)(featb + (size_t)sidx * D_FEAT) + col);
                    a0 = fmaf(w, __uint_as_float(d << 16), a0);
                    a1 = fmaf(w, __uint_as_float(d & 0xFFFF0000u), a1);
                } else {
                    vf2 fv = *((const vf2*)(feat + (size_t)sidx * D_FEAT) + col);
                    a0 = fmaf(w, fv.x, a0);
                    a1 = fmaf(w, fv.y, a1);
                }
            }
        }
        a0 += __shfl_xor(a0, 32);
        a1 += __shfl_xor(a1, 32);
        const int node = b * BUCK_NODES + r;
        if (half == 0 && node < N_NODES) {
            vf2 o = {a0 + b2.x, a1 + b2.y};
            __builtin_nontemporal_store(o, (vf2*)(out + (size_t)node * D_FEAT) + col);
        }
    }
    __syncthreads();

    // tail (nTot > GB_CAP; ~never at 16 sigma): deterministic set, after the
    // epilogue barrier so atomics land on the stored rows.
    if (nTot > GB_CAP) {
        int g2 = base;
        for (int e = o00; e < o01; ++e, ++g2)
            if (g2 >= GB_CAP) {
                vi2 v = ep[c0 * CHUNK + e];
                int node = b * BUCK_NODES + (int)((unsigned)v.x >> 24);
                float w = __int_as_float(v.y);
                int sidx = v.x & 0xFFFFFF;
                for (int d2 = 0; d2 < D_FEAT; ++d2)
                    atomicAdd(&out[(size_t)node * D_FEAT + d2], w * feat[(size_t)sidx * D_FEAT + d2]);
            }
        for (int e = o10; e < o11; ++e, ++g2)
            if (g2 >= GB_CAP) {
                vi2 v = ep[c1 * CHUNK + e];
                int node = b * BUCK_NODES + (int)((unsigned)v.x >> 24);
                float w = __int_as_float(v.y);
                int sidx = v.x & 0xFFFFFF;
                for (int d2 = 0; d2 < D_FEAT; ++d2)
                    atomicAdd(&out[(size_t)node * D_FEAT + d2], w * feat[(size_t)sidx * D_FEAT + d2]);
            }
    }
}

// ---------------- fallback (ws too small): direct atomic path ---------------
__global__ void init_out_kernel(const float* __restrict__ bias,
                                float* __restrict__ out) {
    int i = blockIdx.x * blockDim.x + threadIdx.x;
    if (i < N_NODES * D_FEAT) out[i] = bias[i & (D_FEAT - 1)];
}

__global__ void edge_scatter_kernel(const float* __restrict__ feat,
                                    const float* __restrict__ weight,
                                    const int* __restrict__ src,
                                    const int* __restrict__ dst,
                                    float* __restrict__ out) {
    int e = blockIdx.x * 4 + (threadIdx.x >> 6);
    int lane = threadIdx.x & 63;
    if (e < N_EDGES) {
        atomicAdd(&out[dst[e] * D_FEAT + lane], weight[e] * feat[src[e] * D_FEAT + lane]);
    }
}

extern "C" void kernel_launch(void* const* d_in, const int* in_sizes, int n_in,
                              void* d_out, int out_size, void* d_ws, size_t ws_size,
                              hipStream_t stream) {
    const float* feat   = (const float*)d_in[0];
    const float* weight = (const float*)d_in[1];
    const float* bias   = (const float*)d_in[2];
    const int*   src    = (const int*)d_in[3];
    const int*   dst    = (const int*)d_in[4];
    float* out = (float*)d_out;

    if (ws_size < WS_MED) {
        int total = N_NODES * D_FEAT;
        init_out_kernel<<<(total + 255) / 256, 256, 0, stream>>>(bias, out);
        edge_scatter_kernel<<<(N_EDGES + 3) / 4, 256, 0, stream>>>(feat, weight, src, dst, out);
        return;
    }

    char* ws = (char*)d_ws;
    ushort_t* tbl   = (ushort_t*)(ws + OFF_TBL);
    vi2*      ep    = (vi2*)(ws + OFF_EP);
    ushort_t* featb = (ushort_t*)(ws + OFF_FEATB);
    const bool use_bf16 = (ws_size >= WS_FULL);

    if (use_bf16) {
        k_bin<1><<<NCHUNK + PREP_BLOCKS, BIN_BLK, 0, stream>>>(src, dst, weight, feat, featb, tbl, ep);
        k_sgather<1><<<NBUCK, GB_BLK, 0, stream>>>(feat, featb, bias, tbl, ep, out);
    } else {
        k_bin<0><<<NCHUNK, BIN_BLK, 0, stream>>>(src, dst, weight, feat, featb, tbl, ep);
        k_sgather<0><<<NBUCK, GB_BLK, 0, stream>>>(feat, featb, bias, tbl, ep, out);
    }
}